// Round 1
// baseline (214.686 us; speedup 1.0000x reference)
//
#include <hip/hip_runtime.h>

// YOLOv1 loss, S=14, B=2, C=20, N=30 channels, BATCH=4096.
// One thread per grid cell; memory-bound streaming reduction.

#define NCH 30
#define NCELLS (4096 * 14 * 14)

__global__ void zero_out_kernel(float* out) { out[0] = 0.0f; }

__global__ __launch_bounds__(256) void yolo_loss_kernel(
    const float* __restrict__ pred, const float* __restrict__ target,
    float* __restrict__ out, int ncells)
{
    const int cell = blockIdx.x * blockDim.x + threadIdx.x;
    float local = 0.0f;

    if (cell < ncells) {
        const float* p = pred   + (size_t)cell * NCH;
        const float* t = target + (size_t)cell * NCH;
        // cell*120 bytes is 8B-aligned -> float2 loads (dwordx2)
        const float2* p2 = (const float2*)p;
        const float2* t2 = (const float2*)t;
        float pv[NCH], tv[NCH];
        #pragma unroll
        for (int i = 0; i < 15; ++i) {
            float2 a = p2[i]; pv[2*i] = a.x; pv[2*i+1] = a.y;
            float2 b = t2[i]; tv[2*i] = b.x; tv[2*i+1] = b.y;
        }

        const float invS = 1.0f / 14.0f;
        const float tobj = tv[4];
        const bool  obj  = tobj > 0.0f;

        // target box (box 0; boxes are tiled) -> xyxy
        float tcx = tv[0] * invS, tcy = tv[1] * invS;
        float thw = 0.5f * tv[2], thh = 0.5f * tv[3];
        float tx1 = tcx - thw, ty1 = tcy - thh;
        float tx2 = tcx + thw, ty2 = tcy + thh;
        float area_t = (tx2 - tx1) * (ty2 - ty1);

        float iou0, iou1;
        #pragma unroll
        for (int b = 0; b < 2; ++b) {
            float bx = pv[5*b + 0], by = pv[5*b + 1];
            float bw = pv[5*b + 2], bh = pv[5*b + 3];
            float cx = bx * invS, cy = by * invS;
            float hw = 0.5f * bw, hh = 0.5f * bh;
            float x1 = cx - hw, y1 = cy - hh, x2 = cx + hw, y2 = cy + hh;
            float lx = fmaxf(x1, tx1), ly = fmaxf(y1, ty1);
            float rx = fminf(x2, tx2), ry = fminf(y2, ty2);
            float w = fmaxf(rx - lx, 0.0f), h = fmaxf(ry - ly, 0.0f);
            float inter = w * h;
            float area_p = (x2 - x1) * (y2 - y1);
            float iou = inter / (area_p + area_t - inter);
            if (b == 0) iou0 = iou; else iou1 = iou;
        }
        // jnp.argmax: first max wins -> idx=1 only on strict greater
        const bool  sel     = iou1 > iou0;
        const float max_iou = fmaxf(iou0, iou1);

        if (obj) {
            // responsible predictor via cndmask selects (no dynamic reg indexing)
            float pbx = sel ? pv[5] : pv[0];
            float pby = sel ? pv[6] : pv[1];
            float pbw = sel ? pv[7] : pv[2];
            float pbh = sel ? pv[8] : pv[3];
            float pbc = sel ? pv[9] : pv[4];

            float dx = pbx - tv[0], dy = pby - tv[1];
            float loss_xy = dx*dx + dy*dy;

            float sw = sqrtf(pbw) - sqrtf(tv[2]);
            float sh = sqrtf(pbh) - sqrtf(tv[3]);
            float loss_wh = sw*sw + sh*sh;

            float dob = pbc - max_iou;
            float loss_obj = dob * dob;

            float loss_cls = 0.0f;
            #pragma unroll
            for (int c = 0; c < 20; ++c) {
                float d = pv[10 + c] - tv[10 + c];
                loss_cls = fmaf(d, d, loss_cls);
            }
            local = 5.0f * (loss_xy + loss_wh) + loss_obj + loss_cls;
        } else {
            // noobj: both predictors' confidences vs tiled target conf (==0 here)
            float d0 = pv[4] - tv[4];
            float d1 = pv[9] - tv[9];
            local = 0.5f * (d0*d0 + d1*d1);
        }
    }

    // wave-64 shuffle reduction
    #pragma unroll
    for (int off = 32; off > 0; off >>= 1)
        local += __shfl_down(local, off, 64);

    __shared__ float wsum[4];
    const int lane = threadIdx.x & 63;
    const int wid  = threadIdx.x >> 6;
    if (lane == 0) wsum[wid] = local;
    __syncthreads();
    if (threadIdx.x == 0) {
        float s = wsum[0] + wsum[1] + wsum[2] + wsum[3];
        atomicAdd(out, s * (1.0f / 4096.0f));
    }
}

extern "C" void kernel_launch(void* const* d_in, const int* in_sizes, int n_in,
                              void* d_out, int out_size, void* d_ws, size_t ws_size,
                              hipStream_t stream) {
    const float* pred   = (const float*)d_in[0];
    const float* target = (const float*)d_in[1];
    float* out = (float*)d_out;

    const int ncells = in_sizes[0] / NCH;  // 802816

    zero_out_kernel<<<1, 1, 0, stream>>>(out);
    const int block = 256;
    const int grid  = (ncells + block - 1) / block;  // 3136
    yolo_loss_kernel<<<grid, block, 0, stream>>>(pred, target, out, ncells);
}

// Round 2
// 201.740 us; speedup vs baseline: 1.0642x; 1.0642x over previous
//
#include <hip/hip_runtime.h>

// YOLOv1 loss, S=14, B=2, C=20, 30 fp32 channels/cell, 802816 cells.
// Memory-bound. Per-wave LDS staging: wave loads its 64 cells' 7680 B
// as a linear coalesced block (float4), then lanes read their own cell
// from LDS. 802816 = 3136 blocks x 256 threads exactly (no tail).

__global__ void zero_out_kernel(float* out) { out[0] = 0.0f; }

__global__ __launch_bounds__(256) void yolo_loss_kernel(
    const float* __restrict__ pred, const float* __restrict__ target,
    float* __restrict__ out)
{
    __shared__ float sp[4][1920];   // 4 waves x 64 cells x 30 ch
    __shared__ float st[4][1920];   // total LDS = 61440 B -> 2 blocks/CU

    const int lane = threadIdx.x & 63;
    const int wid  = threadIdx.x >> 6;
    const size_t tile0 = ((size_t)blockIdx.x * 4 + wid) * 64;  // first cell of wave tile
    const float* gp = pred   + tile0 * 30;
    const float* gt = target + tile0 * 30;

    // ---- global -> regs, fully coalesced (7x dwordx4 + 1x dwordx2 per array)
    float4 rp4[7], rt4[7];
    const float4* gp4 = (const float4*)gp;
    const float4* gt4 = (const float4*)gt;
    #pragma unroll
    for (int i = 0; i < 7; ++i) {
        rp4[i] = gp4[i*64 + lane];
        rt4[i] = gt4[i*64 + lane];
    }
    float2 rp2 = ((const float2*)gp)[896 + lane];
    float2 rt2 = ((const float2*)gt)[896 + lane];

    // ---- regs -> LDS (identity copy; cell-major layout is automatic)
    float4* wp4 = (float4*)sp[wid];
    float4* wt4 = (float4*)st[wid];
    #pragma unroll
    for (int i = 0; i < 7; ++i) {
        wp4[i*64 + lane] = rp4[i];
        wt4[i*64 + lane] = rt4[i];
    }
    ((float2*)sp[wid])[896 + lane] = rp2;
    ((float2*)st[wid])[896 + lane] = rt2;
    // wave-private tile: no __syncthreads needed; LDS pipe is in-order per wave

    // ---- LDS -> own cell (15x ds_read_b64 each; 120B stride, ~4-way banks)
    float pv[30], tv[30];
    const float2* rp = (const float2*)&sp[wid][lane * 30];
    const float2* rt = (const float2*)&st[wid][lane * 30];
    #pragma unroll
    for (int j = 0; j < 15; ++j) {
        float2 a = rp[j]; pv[2*j] = a.x; pv[2*j+1] = a.y;
        float2 b = rt[j]; tv[2*j] = b.x; tv[2*j+1] = b.y;
    }

    // ---- per-cell loss (identical math to the verified round-1 kernel)
    const float invS = 1.0f / 14.0f;
    const bool obj = tv[4] > 0.0f;

    float tcx = tv[0] * invS, tcy = tv[1] * invS;
    float thw = 0.5f * tv[2], thh = 0.5f * tv[3];
    float tx1 = tcx - thw, ty1 = tcy - thh;
    float tx2 = tcx + thw, ty2 = tcy + thh;
    float area_t = (tx2 - tx1) * (ty2 - ty1);

    float iou0 = 0.0f, iou1 = 0.0f;
    #pragma unroll
    for (int b = 0; b < 2; ++b) {
        float cx = pv[5*b + 0] * invS, cy = pv[5*b + 1] * invS;
        float hw = 0.5f * pv[5*b + 2], hh = 0.5f * pv[5*b + 3];
        float x1 = cx - hw, y1 = cy - hh, x2 = cx + hw, y2 = cy + hh;
        float lx = fmaxf(x1, tx1), ly = fmaxf(y1, ty1);
        float rx = fminf(x2, tx2), ry = fminf(y2, ty2);
        float w = fmaxf(rx - lx, 0.0f), h = fmaxf(ry - ly, 0.0f);
        float inter = w * h;
        float area_p = (x2 - x1) * (y2 - y1);
        float iou = inter / (area_p + area_t - inter);
        if (b == 0) iou0 = iou; else iou1 = iou;
    }
    const bool  sel     = iou1 > iou0;          // jnp.argmax: first max wins
    const float max_iou = fmaxf(iou0, iou1);

    float local;
    if (obj) {
        float pbx = sel ? pv[5] : pv[0];
        float pby = sel ? pv[6] : pv[1];
        float pbw = sel ? pv[7] : pv[2];
        float pbh = sel ? pv[8] : pv[3];
        float pbc = sel ? pv[9] : pv[4];

        float dx = pbx - tv[0], dy = pby - tv[1];
        float loss_xy = dx*dx + dy*dy;

        float sw = sqrtf(pbw) - sqrtf(tv[2]);
        float sh = sqrtf(pbh) - sqrtf(tv[3]);
        float loss_wh = sw*sw + sh*sh;

        float dob = pbc - max_iou;
        float loss_obj = dob * dob;

        float loss_cls = 0.0f;
        #pragma unroll
        for (int c = 0; c < 20; ++c) {
            float d = pv[10 + c] - tv[10 + c];
            loss_cls = fmaf(d, d, loss_cls);
        }
        local = 5.0f * (loss_xy + loss_wh) + loss_obj + loss_cls;
    } else {
        float d0 = pv[4] - tv[4];
        float d1 = pv[9] - tv[9];
        local = 0.5f * (d0*d0 + d1*d1);
    }

    // ---- wave-64 shuffle reduction -> block -> one atomic
    #pragma unroll
    for (int off = 32; off > 0; off >>= 1)
        local += __shfl_down(local, off, 64);

    __shared__ float wsum[4];
    if (lane == 0) wsum[wid] = local;
    __syncthreads();
    if (threadIdx.x == 0) {
        float s = wsum[0] + wsum[1] + wsum[2] + wsum[3];
        atomicAdd(out, s * (1.0f / 4096.0f));
    }
}

extern "C" void kernel_launch(void* const* d_in, const int* in_sizes, int n_in,
                              void* d_out, int out_size, void* d_ws, size_t ws_size,
                              hipStream_t stream) {
    const float* pred   = (const float*)d_in[0];
    const float* target = (const float*)d_in[1];
    float* out = (float*)d_out;

    zero_out_kernel<<<1, 1, 0, stream>>>(out);
    yolo_loss_kernel<<<3136, 256, 0, stream>>>(pred, target, out);
}